// Round 1
// baseline (504.028 us; speedup 1.0000x reference)
//
#include <hip/hip_runtime.h>
#include <math.h>

#define DIMC 512
#define HIDD 64
#define NB   8
#define SS   96
#define NROWS (NB*SS*SS)      // 73728
#define QN   ((size_t)NROWS*HIDD)   // 4718592
#define MAXKN (SS*SS*HIDD)    // 589824
#define EWBN  (SS*SS)         // 9216

// ---------------- K1: QKV projection GEMM ----------------
// C[n, d] = sum_c x[n,c] * w[d,c] + b[d]   for w in {wq,wk,wv} (blockIdx.y)
// BM=128 rows, BN=64 (full HID), BK=32. 256 threads, 8x4 per-thread tile.
__global__ __launch_bounds__(256) void qkv_gemm(
    const float* __restrict__ x,
    const float* __restrict__ wq, const float* __restrict__ wqb,
    const float* __restrict__ wk, const float* __restrict__ wkb,
    const float* __restrict__ wv, const float* __restrict__ wvb,
    float* __restrict__ qo, float* __restrict__ ko, float* __restrict__ vo)
{
    __shared__ float At[32][132];   // [k][row], 132 pad (16B-aligned rows)
    __shared__ float Bt[32][68];    // [k][col]

    const float* w; const float* bias; float* o;
    if (blockIdx.y == 0)      { w = wq; bias = wqb; o = qo; }
    else if (blockIdx.y == 1) { w = wk; bias = wkb; o = ko; }
    else                      { w = wv; bias = wvb; o = vo; }

    const int tid  = threadIdx.x;
    const int row0 = blockIdx.x * 128;
    const int ty   = tid >> 4;     // 0..15 -> rows ty*8..+7
    const int tx   = tid & 15;     // 0..15 -> cols tx*4..+3

    float acc[8][4];
    #pragma unroll
    for (int i = 0; i < 8; ++i)
        #pragma unroll
        for (int j = 0; j < 4; ++j) acc[i][j] = 0.f;

    for (int k0 = 0; k0 < DIMC; k0 += 32) {
        // stage A: 128 rows x 32 k  (1024 float4, 4 per thread)
        #pragma unroll
        for (int p = 0; p < 4; ++p) {
            int f = tid + p*256;
            int row = f >> 3, kq = f & 7;
            const float4 xv = *reinterpret_cast<const float4*>(
                x + (size_t)(row0 + row)*DIMC + k0 + kq*4);
            At[kq*4+0][row] = xv.x;
            At[kq*4+1][row] = xv.y;
            At[kq*4+2][row] = xv.z;
            At[kq*4+3][row] = xv.w;
        }
        // stage B: 64 cols x 32 k (512 float4, 2 per thread)
        #pragma unroll
        for (int p = 0; p < 2; ++p) {
            int f = tid + p*256;
            int col = f >> 3, kq = f & 7;
            const float4 wv4 = *reinterpret_cast<const float4*>(
                w + (size_t)col*DIMC + k0 + kq*4);
            Bt[kq*4+0][col] = wv4.x;
            Bt[kq*4+1][col] = wv4.y;
            Bt[kq*4+2][col] = wv4.z;
            Bt[kq*4+3][col] = wv4.w;
        }
        __syncthreads();

        #pragma unroll
        for (int kk = 0; kk < 32; ++kk) {
            const float4 a0 = *reinterpret_cast<const float4*>(&At[kk][ty*8]);
            const float4 a1 = *reinterpret_cast<const float4*>(&At[kk][ty*8+4]);
            const float4 b4 = *reinterpret_cast<const float4*>(&Bt[kk][tx*4]);
            const float a[8] = {a0.x,a0.y,a0.z,a0.w,a1.x,a1.y,a1.z,a1.w};
            const float b[4] = {b4.x,b4.y,b4.z,b4.w};
            #pragma unroll
            for (int i = 0; i < 8; ++i)
                #pragma unroll
                for (int j = 0; j < 4; ++j)
                    acc[i][j] += a[i]*b[j];
        }
        __syncthreads();
    }

    const float4 bias4 = *reinterpret_cast<const float4*>(bias + tx*4);
    #pragma unroll
    for (int i = 0; i < 8; ++i) {
        float4 ov;
        ov.x = acc[i][0] + bias4.x;
        ov.y = acc[i][1] + bias4.y;
        ov.z = acc[i][2] + bias4.z;
        ov.w = acc[i][3] + bias4.w;
        *reinterpret_cast<float4*>(
            o + (size_t)(row0 + ty*8 + i)*HIDD + tx*4) = ov;
    }
}

// ---------------- K2: batch-max of k + exp(w_bias) ----------------
__global__ void maxk_expwb(const float* __restrict__ kin,
                           const float* __restrict__ wbias,
                           float* __restrict__ mk,
                           float* __restrict__ ewb)
{
    int idx = blockIdx.x*256 + threadIdx.x;
    if (idx < MAXKN) {
        float m = kin[idx];
        #pragma unroll
        for (int b = 1; b < NB; ++b)
            m = fmaxf(m, kin[(size_t)b*MAXKN + idx]);
        mk[idx] = m;
    } else {
        int e = idx - MAXKN;
        ewb[e] = __expf(wbias[e]);   // grid sized exactly: e < EWBN
    }
}

// ---------------- K3: per-(b,h) AFT core ----------------
// num[i,d] = sum_w ewb[i,w]*ek[w,d]*v[w,d]; den likewise; y=sigmoid(q)*num/den
__global__ __launch_bounds__(256) void aft_core(
    const float* __restrict__ q, const float* __restrict__ kin,
    const float* __restrict__ v, const float* __restrict__ mk,
    const float* __restrict__ ewb, float* __restrict__ y)
{
    __shared__ float ew_s[96][97];   // [w][i] = ewb[i][w] (transposed)
    __shared__ float ek_s[96][68];   // [w][d]
    __shared__ float ekv_s[96][68];  // [w][d]

    const int tid  = threadIdx.x;
    const int bh   = blockIdx.x;            // 0..767
    const int h    = bh % SS;
    const size_t base  = (size_t)bh * (SS*HIDD);
    const size_t mbase = (size_t)h  * (SS*HIDD);

    for (int idx = tid; idx < EWBN; idx += 256) {
        int i = idx / 96, wi = idx - i*96;
        ew_s[wi][i] = ewb[idx];
    }
    #pragma unroll
    for (int p = 0; p < 6; ++p) {           // 1536 float4
        int f = tid + p*256;
        int wi = f >> 4, dq = f & 15;
        const float4 k4 = *reinterpret_cast<const float4*>(kin + base  + wi*64 + dq*4);
        const float4 m4 = *reinterpret_cast<const float4*>(mk  + mbase + wi*64 + dq*4);
        const float4 v4 = *reinterpret_cast<const float4*>(v   + base  + wi*64 + dq*4);
        float e0 = __expf(k4.x - m4.x);
        float e1 = __expf(k4.y - m4.y);
        float e2 = __expf(k4.z - m4.z);
        float e3 = __expf(k4.w - m4.w);
        ek_s [wi][dq*4+0] = e0;      ek_s [wi][dq*4+1] = e1;
        ek_s [wi][dq*4+2] = e2;      ek_s [wi][dq*4+3] = e3;
        ekv_s[wi][dq*4+0] = e0*v4.x; ekv_s[wi][dq*4+1] = e1*v4.y;
        ekv_s[wi][dq*4+2] = e2*v4.z; ekv_s[wi][dq*4+3] = e3*v4.w;
    }
    __syncthreads();

    const int ti = tid >> 4;   // 0..15 -> i rows ti*6..+5
    const int td = tid & 15;   // 0..15 -> d cols td*4..+3
    float accn[6][4], accd[6][4];
    #pragma unroll
    for (int j = 0; j < 6; ++j)
        #pragma unroll
        for (int d = 0; d < 4; ++d) { accn[j][d] = 0.f; accd[j][d] = 0.f; }

    #pragma unroll 4
    for (int wi = 0; wi < 96; ++wi) {
        const float4 bn = *reinterpret_cast<const float4*>(&ekv_s[wi][td*4]);
        const float4 bd = *reinterpret_cast<const float4*>(&ek_s [wi][td*4]);
        const float bnv[4] = {bn.x,bn.y,bn.z,bn.w};
        const float bdv[4] = {bd.x,bd.y,bd.z,bd.w};
        #pragma unroll
        for (int j = 0; j < 6; ++j) {
            const float a = ew_s[wi][ti*6 + j];
            #pragma unroll
            for (int d = 0; d < 4; ++d) {
                accn[j][d] += a*bnv[d];
                accd[j][d] += a*bdv[d];
            }
        }
    }

    #pragma unroll
    for (int j = 0; j < 6; ++j) {
        const int i = ti*6 + j;
        const float4 q4 = *reinterpret_cast<const float4*>(q + base + i*64 + td*4);
        float4 ov;
        ov.x = (1.f/(1.f+__expf(-q4.x))) * accn[j][0]/accd[j][0];
        ov.y = (1.f/(1.f+__expf(-q4.y))) * accn[j][1]/accd[j][1];
        ov.z = (1.f/(1.f+__expf(-q4.z))) * accn[j][2]/accd[j][2];
        ov.w = (1.f/(1.f+__expf(-q4.w))) * accn[j][3]/accd[j][3];
        *reinterpret_cast<float4*>(y + base + i*64 + td*4) = ov;
    }
}

// ---------------- K4: output GEMM ----------------
// out[n,c] = sum_d y[n,d]*ow[c,d] + ob[c]. BM=64, BN=128, K=64 full.
__global__ __launch_bounds__(256) void out_gemm(
    const float* __restrict__ y, const float* __restrict__ ow,
    const float* __restrict__ ob, float* __restrict__ out)
{
    __shared__ float Yt[64][68];    // [d][row]
    __shared__ float Wt[64][132];   // [d][col]

    const int tid  = threadIdx.x;
    const int row0 = blockIdx.x * 64;
    const int c0   = blockIdx.y * 128;

    #pragma unroll
    for (int p = 0; p < 4; ++p) {   // 1024 float4 of Y
        int f = tid + p*256;
        int row = f >> 4, dq = f & 15;
        const float4 y4 = *reinterpret_cast<const float4*>(
            y + (size_t)(row0 + row)*HIDD + dq*4);
        Yt[dq*4+0][row] = y4.x; Yt[dq*4+1][row] = y4.y;
        Yt[dq*4+2][row] = y4.z; Yt[dq*4+3][row] = y4.w;
    }
    #pragma unroll
    for (int p = 0; p < 8; ++p) {   // 2048 float4 of W
        int f = tid + p*256;
        int col = f >> 4, dq = f & 15;
        const float4 w4 = *reinterpret_cast<const float4*>(
            ow + (size_t)(c0 + col)*HIDD + dq*4);
        Wt[dq*4+0][col] = w4.x; Wt[dq*4+1][col] = w4.y;
        Wt[dq*4+2][col] = w4.z; Wt[dq*4+3][col] = w4.w;
    }
    __syncthreads();

    const int ty = tid >> 5;   // 0..7  -> rows ty*8..+7
    const int tx = tid & 31;   // 0..31 -> cols tx*4..+3
    float acc[8][4];
    #pragma unroll
    for (int i = 0; i < 8; ++i)
        #pragma unroll
        for (int j = 0; j < 4; ++j) acc[i][j] = 0.f;

    #pragma unroll 8
    for (int d = 0; d < 64; ++d) {
        const float4 a0 = *reinterpret_cast<const float4*>(&Yt[d][ty*8]);
        const float4 a1 = *reinterpret_cast<const float4*>(&Yt[d][ty*8+4]);
        const float4 b4 = *reinterpret_cast<const float4*>(&Wt[d][tx*4]);
        const float a[8] = {a0.x,a0.y,a0.z,a0.w,a1.x,a1.y,a1.z,a1.w};
        const float b[4] = {b4.x,b4.y,b4.z,b4.w};
        #pragma unroll
        for (int i = 0; i < 8; ++i)
            #pragma unroll
            for (int j = 0; j < 4; ++j)
                acc[i][j] += a[i]*b[j];
    }

    const float4 ob4 = *reinterpret_cast<const float4*>(ob + c0 + tx*4);
    #pragma unroll
    for (int i = 0; i < 8; ++i) {
        float4 ov;
        ov.x = acc[i][0] + ob4.x;
        ov.y = acc[i][1] + ob4.y;
        ov.z = acc[i][2] + ob4.z;
        ov.w = acc[i][3] + ob4.w;
        *reinterpret_cast<float4*>(
            out + (size_t)(row0 + ty*8 + i)*DIMC + c0 + tx*4) = ov;
    }
}

extern "C" void kernel_launch(void* const* d_in, const int* in_sizes, int n_in,
                              void* d_out, int out_size, void* d_ws, size_t ws_size,
                              hipStream_t stream)
{
    const float* x   = (const float*)d_in[0];
    const float* wqw = (const float*)d_in[1];
    const float* wqb = (const float*)d_in[2];
    const float* wkw = (const float*)d_in[3];
    const float* wkb = (const float*)d_in[4];
    const float* wvw = (const float*)d_in[5];
    const float* wvb = (const float*)d_in[6];
    const float* ow  = (const float*)d_in[7];
    const float* ob  = (const float*)d_in[8];
    const float* wbt = (const float*)d_in[9];
    float* out = (float*)d_out;
    float* ws  = (float*)d_ws;

    float* q   = ws;
    float* kb  = ws + QN;
    float* vb  = ws + 2*QN;
    float* yb  = ws + 3*QN;
    float* mk  = ws + 4*QN;
    float* ewb = mk + MAXKN;

    qkv_gemm  <<<dim3(NROWS/128, 3), 256, 0, stream>>>(x, wqw, wqb, wkw, wkb, wvw, wvb, q, kb, vb);
    maxk_expwb<<<(MAXKN + EWBN)/256, 256, 0, stream>>>(kb, wbt, mk, ewb);
    aft_core  <<<NB*SS, 256, 0, stream>>>(q, kb, vb, mk, ewb, yb);
    out_gemm  <<<dim3(NROWS/64, 4), 256, 0, stream>>>(yb, ow, ob, out);
}

// Round 6
// 372.560 us; speedup vs baseline: 1.3529x; 1.3529x over previous
//
#include <hip/hip_runtime.h>
#include <hip/hip_bf16.h>
#include <math.h>

#define DIMC 512
#define HIDD 64
#define NB   8
#define SS   96
#define NROWS (NB*SS*SS)            // 73728
#define QN   ((size_t)NROWS*HIDD)   // 4718592
#define MAXKN (SS*SS*HIDD)          // 589824
#define EWBN  (SS*SS)               // 9216
#define WBF_FLOATS 65536            // 131072 shorts: wq|wk|wv|ow in bf16

typedef short short8v __attribute__((ext_vector_type(8)));
typedef short short4v __attribute__((ext_vector_type(4)));
typedef float f32x4  __attribute__((ext_vector_type(4)));

__device__ __forceinline__ short f2bf(float f) {
    __hip_bfloat16 h = __float2bfloat16(f);   // RTN-E
    return *reinterpret_cast<short*>(&h);
}

// ---------------- K0: weights fp32 -> bf16 (wq|wk|wv|ow concatenated) -------
__global__ void wcvt(const float* __restrict__ wq, const float* __restrict__ wk,
                     const float* __restrict__ wv, const float* __restrict__ ow,
                     short* __restrict__ wbf)
{
    int idx = blockIdx.x*256 + threadIdx.x;   // 131072 total
    const int W = HIDD*DIMC;                  // 32768
    float v;
    if (idx < W)            v = wq[idx];
    else if (idx < 2*W)     v = wk[idx - W];
    else if (idx < 3*W)     v = wv[idx - 2*W];
    else                    v = ow[idx - 3*W];
    wbf[idx] = f2bf(v);
}

// ---------------- K1: fused QKV projection, bf16 MFMA ----------------
// A = x[128 rows][512], B rows 0..191 = bf16(wq|wk|wv) rows. C = A * B^T.
__global__ __launch_bounds__(256) void qkv_mfma(
    const float* __restrict__ x, const short* __restrict__ wbf,
    const float* __restrict__ wqb, const float* __restrict__ wkb,
    const float* __restrict__ wvb,
    float* __restrict__ qo, float* __restrict__ ko, float* __restrict__ vo)
{
    __shared__ short As[128][72];   // +8 pad: frag reads land 2-way (free)
    __shared__ short Bs[192][72];

    const int tid  = threadIdx.x;
    const int lane = tid & 63;
    const int wid  = tid >> 6;
    const int wy   = wid >> 1, wx = wid & 1;
    const int l15  = lane & 15, lg = lane >> 4;
    const int row0 = blockIdx.x * 128;

    f32x4 acc[4][6];
    #pragma unroll
    for (int m = 0; m < 4; ++m)
        #pragma unroll
        for (int n = 0; n < 6; ++n) acc[m][n] = (f32x4)0.f;

    for (int k0 = 0; k0 < DIMC; k0 += 64) {
        // stage A: 128x64 fp32 -> bf16. 2048 float4, 8/thread.
        #pragma unroll
        for (int p = 0; p < 8; ++p) {
            int f = tid + p*256;
            int row = f >> 4, qq = f & 15;
            const float4 xv = *reinterpret_cast<const float4*>(
                x + (size_t)(row0 + row)*DIMC + k0 + qq*4);
            short4v s;
            s.x = f2bf(xv.x); s.y = f2bf(xv.y); s.z = f2bf(xv.z); s.w = f2bf(xv.w);
            *reinterpret_cast<short4v*>(&As[row][qq*4]) = s;
        }
        // stage B: 192x64 bf16 copy. 1536 short8, 6/thread.
        #pragma unroll
        for (int p = 0; p < 6; ++p) {
            int f = tid + p*256;
            int row = f >> 3, qq = f & 7;
            const short8v wv8 = *reinterpret_cast<const short8v*>(
                wbf + (size_t)row*DIMC + k0 + qq*8);
            *reinterpret_cast<short8v*>(&Bs[row][qq*8]) = wv8;
        }
        __syncthreads();

        #pragma unroll
        for (int ks = 0; ks < 2; ++ks) {
            short8v ar[4], br[6];
            #pragma unroll
            for (int m = 0; m < 4; ++m)
                ar[m] = *reinterpret_cast<const short8v*>(
                    &As[wy*64 + m*16 + l15][ks*32 + lg*8]);
            #pragma unroll
            for (int n = 0; n < 6; ++n)
                br[n] = *reinterpret_cast<const short8v*>(
                    &Bs[wx*96 + n*16 + l15][ks*32 + lg*8]);
            #pragma unroll
            for (int m = 0; m < 4; ++m)
                #pragma unroll
                for (int n = 0; n < 6; ++n)
                    acc[m][n] = __builtin_amdgcn_mfma_f32_16x16x32_bf16(
                        ar[m], br[n], acc[m][n], 0, 0, 0);
        }
        __syncthreads();
    }

    // epilogue: C/D layout col=lane&15, row=(lane>>4)*4+reg (m89-verified)
    #pragma unroll
    for (int n = 0; n < 6; ++n) {
        const int col192 = wx*96 + n*16 + l15;
        const int sel = col192 >> 6;          // uniform per (wx,n)
        const int c   = col192 & 63;
        float* o = (sel == 0) ? qo : (sel == 1) ? ko : vo;
        const float* bp = (sel == 0) ? wqb : (sel == 1) ? wkb : wvb;
        const float bv = bp[c];
        #pragma unroll
        for (int m = 0; m < 4; ++m)
            #pragma unroll
            for (int r = 0; r < 4; ++r) {
                const int row = row0 + wy*64 + m*16 + lg*4 + r;
                o[(size_t)row*HIDD + c] = acc[m][n][r] + bv;
            }
    }
}

// ---------------- K2: batch-max of k + exp(w_bias) ----------------
__global__ void maxk_expwb(const float* __restrict__ kin,
                           const float* __restrict__ wbias,
                           float* __restrict__ mk,
                           float* __restrict__ ewb)
{
    int idx = blockIdx.x*256 + threadIdx.x;
    if (idx < MAXKN) {
        float m = kin[idx];
        #pragma unroll
        for (int b = 1; b < NB; ++b)
            m = fmaxf(m, kin[(size_t)b*MAXKN + idx]);
        mk[idx] = m;
    } else {
        int e = idx - MAXKN;
        ewb[e] = __expf(wbias[e]);
    }
}

// ---------------- K3: per-(b,h) AFT core; y written as bf16 ----------------
__global__ __launch_bounds__(256) void aft_core(
    const float* __restrict__ q, const float* __restrict__ kin,
    const float* __restrict__ v, const float* __restrict__ mk,
    const float* __restrict__ ewb, short* __restrict__ y)
{
    __shared__ float ew_s[96][97];
    __shared__ float ek_s[96][68];
    __shared__ float ekv_s[96][68];

    const int tid  = threadIdx.x;
    const int bh   = blockIdx.x;
    const int h    = bh % SS;
    const size_t base  = (size_t)bh * (SS*HIDD);
    const size_t mbase = (size_t)h  * (SS*HIDD);

    for (int idx = tid; idx < EWBN; idx += 256) {
        int i = idx / 96, wi = idx - i*96;
        ew_s[wi][i] = ewb[idx];
    }
    #pragma unroll
    for (int p = 0; p < 6; ++p) {
        int f = tid + p*256;
        int wi = f >> 4, dq = f & 15;
        const float4 k4 = *reinterpret_cast<const float4*>(kin + base  + wi*64 + dq*4);
        const float4 m4 = *reinterpret_cast<const float4*>(mk  + mbase + wi*64 + dq*4);
        const float4 v4 = *reinterpret_cast<const float4*>(v   + base  + wi*64 + dq*4);
        float e0 = __expf(k4.x - m4.x);
        float e1 = __expf(k4.y - m4.y);
        float e2 = __expf(k4.z - m4.z);
        float e3 = __expf(k4.w - m4.w);
        ek_s [wi][dq*4+0] = e0;      ek_s [wi][dq*4+1] = e1;
        ek_s [wi][dq*4+2] = e2;      ek_s [wi][dq*4+3] = e3;
        ekv_s[wi][dq*4+0] = e0*v4.x; ekv_s[wi][dq*4+1] = e1*v4.y;
        ekv_s[wi][dq*4+2] = e2*v4.z; ekv_s[wi][dq*4+3] = e3*v4.w;
    }
    __syncthreads();

    const int ti = tid >> 4;
    const int td = tid & 15;
    float accn[6][4], accd[6][4];
    #pragma unroll
    for (int j = 0; j < 6; ++j)
        #pragma unroll
        for (int d = 0; d < 4; ++d) { accn[j][d] = 0.f; accd[j][d] = 0.f; }

    #pragma unroll 4
    for (int wi = 0; wi < 96; ++wi) {
        const float4 bn = *reinterpret_cast<const float4*>(&ekv_s[wi][td*4]);
        const float4 bd = *reinterpret_cast<const float4*>(&ek_s [wi][td*4]);
        const float bnv[4] = {bn.x,bn.y,bn.z,bn.w};
        const float bdv[4] = {bd.x,bd.y,bd.z,bd.w};
        #pragma unroll
        for (int j = 0; j < 6; ++j) {
            const float a = ew_s[wi][ti*6 + j];
            #pragma unroll
            for (int d = 0; d < 4; ++d) {
                accn[j][d] += a*bnv[d];
                accd[j][d] += a*bdv[d];
            }
        }
    }

    #pragma unroll
    for (int j = 0; j < 6; ++j) {
        const int i = ti*6 + j;
        const float4 q4 = *reinterpret_cast<const float4*>(q + base + i*64 + td*4);
        short4v s;
        s.x = f2bf((1.f/(1.f+__expf(-q4.x))) * accn[j][0]/accd[j][0]);
        s.y = f2bf((1.f/(1.f+__expf(-q4.y))) * accn[j][1]/accd[j][1]);
        s.z = f2bf((1.f/(1.f+__expf(-q4.z))) * accn[j][2]/accd[j][2]);
        s.w = f2bf((1.f/(1.f+__expf(-q4.w))) * accn[j][3]/accd[j][3]);
        *reinterpret_cast<short4v*>(y + base + i*64 + td*4) = s;
    }
}

// ---------------- K4: output GEMM, bf16 MFMA ----------------
// out[n,c] = sum_d y[n,d]*ow[c,d] + ob[c].  BM=128, BN=128, K=64 (2 MFMA steps)
__global__ __launch_bounds__(256) void out_mfma(
    const short* __restrict__ y, const short* __restrict__ owbf,
    const float* __restrict__ ob, float* __restrict__ out)
{
    __shared__ short As[128][72];
    __shared__ short Bs[128][72];

    const int tid  = threadIdx.x;
    const int lane = tid & 63;
    const int wid  = tid >> 6;
    const int wy   = wid >> 1, wx = wid & 1;
    const int l15  = lane & 15, lg = lane >> 4;
    const int row0 = blockIdx.x * 128;
    const int c0   = blockIdx.y * 128;

    // stage A: y bf16, 1024 short8, 4/thread
    #pragma unroll
    for (int p = 0; p < 4; ++p) {
        int f = tid + p*256;
        int row = f >> 3, qq = f & 7;
        const short8v yv = *reinterpret_cast<const short8v*>(
            y + (size_t)(row0 + row)*HIDD + qq*8);
        *reinterpret_cast<short8v*>(&As[row][qq*8]) = yv;
    }
    // stage B: ow bf16 rows c0..c0+127, 1024 short8, 4/thread
    #pragma unroll
    for (int p = 0; p < 4; ++p) {
        int f = tid + p*256;
        int row = f >> 3, qq = f & 7;
        const short8v wv8 = *reinterpret_cast<const short8v*>(
            owbf + (size_t)(c0 + row)*HIDD + qq*8);
        *reinterpret_cast<short8v*>(&Bs[row][qq*8]) = wv8;
    }
    __syncthreads();

    f32x4 acc[4][4];
    #pragma unroll
    for (int m = 0; m < 4; ++m)
        #pragma unroll
        for (int n = 0; n < 4; ++n) acc[m][n] = (f32x4)0.f;

    #pragma unroll
    for (int ks = 0; ks < 2; ++ks) {
        short8v ar[4], br[4];
        #pragma unroll
        for (int m = 0; m < 4; ++m)
            ar[m] = *reinterpret_cast<const short8v*>(
                &As[wy*64 + m*16 + l15][ks*32 + lg*8]);
        #pragma unroll
        for (int n = 0; n < 4; ++n)
            br[n] = *reinterpret_cast<const short8v*>(
                &Bs[wx*64 + n*16 + l15][ks*32 + lg*8]);
        #pragma unroll
        for (int m = 0; m < 4; ++m)
            #pragma unroll
            for (int n = 0; n < 4; ++n)
                acc[m][n] = __builtin_amdgcn_mfma_f32_16x16x32_bf16(
                    ar[m], br[n], acc[m][n], 0, 0, 0);
    }

    #pragma unroll
    for (int n = 0; n < 4; ++n) {
        const int c = c0 + wx*64 + n*16 + l15;
        const float bv = ob[c];
        #pragma unroll
        for (int m = 0; m < 4; ++m)
            #pragma unroll
            for (int r = 0; r < 4; ++r) {
                const int row = row0 + wy*64 + m*16 + lg*4 + r;
                out[(size_t)row*DIMC + c] = acc[m][n][r] + bv;
            }
    }
}

extern "C" void kernel_launch(void* const* d_in, const int* in_sizes, int n_in,
                              void* d_out, int out_size, void* d_ws, size_t ws_size,
                              hipStream_t stream)
{
    const float* x   = (const float*)d_in[0];
    const float* wqw = (const float*)d_in[1];
    const float* wqb = (const float*)d_in[2];
    const float* wkw = (const float*)d_in[3];
    const float* wkb = (const float*)d_in[4];
    const float* wvw = (const float*)d_in[5];
    const float* wvb = (const float*)d_in[6];
    const float* ow  = (const float*)d_in[7];
    const float* ob  = (const float*)d_in[8];
    const float* wbt = (const float*)d_in[9];
    float* out = (float*)d_out;
    float* ws  = (float*)d_ws;

    float* q   = ws;
    float* kb  = ws + QN;
    float* vb  = ws + 2*QN;
    float* mk  = ws + 3*QN;
    float* ewb = mk + MAXKN;
    short* wbf = (short*)(ewb + EWBN);             // 131072 shorts
    short* yb  = (short*)(ewb + EWBN + WBF_FLOATS); // QN shorts
    const short* owbf = wbf + 3*HIDD*DIMC;

    wcvt      <<<512, 256, 0, stream>>>(wqw, wkw, wvw, ow, wbf);
    qkv_mfma  <<<NROWS/128, 256, 0, stream>>>(x, wbf, wqb, wkb, wvb, q, kb, vb);
    maxk_expwb<<<(MAXKN + EWBN)/256, 256, 0, stream>>>(kb, wbt, mk, ewb);
    aft_core  <<<NB*SS, 256, 0, stream>>>(q, kb, vb, mk, ewb, yb);
    out_mfma  <<<dim3(NROWS/128, DIMC/128), 256, 0, stream>>>(yb, owbf, ob, out);
}